// Round 11
// baseline (612.501 us; speedup 1.0000x reference)
//
#include <hip/hip_runtime.h>
#include <math.h>

// FineGrainLoss: B=96, n1=196 (image tokens), n2=77 (text tokens), d=512.
#define BB 96
#define N1 196
#define N2 77
#define DD 512

#define IMGN (BB * N1 * DD)
#define TXTN (BB * N2 * DD)

typedef _Float16 f16x8 __attribute__((ext_vector_type(8)));  // 8 f16 (4 VGPR)
typedef float f4v __attribute__((ext_vector_type(4)));       // MFMA C/D

// fp32 -> fp16 convert pass (4 elems/thread).
__global__ void convert_kernel(const float* __restrict__ src,
                               _Float16* __restrict__ dst, int n) {
    int i = (blockIdx.x * blockDim.x + threadIdx.x) * 4;
    if (i >= n) return;
    float4 v = *(const float4*)(src + i);
    union { _Float16 h[4]; uint2 u; } o;
    o.h[0] = (_Float16)v.x; o.h[1] = (_Float16)v.y;
    o.h[2] = (_Float16)v.z; o.h[3] = (_Float16)v.w;
    *(uint2*)(dst + i) = o.u;
}

__device__ __forceinline__ f16x8 cvt8(const float* __restrict__ p) {
    float4 v0 = *(const float4*)p;
    float4 v1 = *(const float4*)(p + 4);
    f16x8 f;
    f[0] = (_Float16)v0.x; f[1] = (_Float16)v0.y;
    f[2] = (_Float16)v0.z; f[3] = (_Float16)v0.w;
    f[4] = (_Float16)v1.x; f[5] = (_Float16)v1.y;
    f[6] = (_Float16)v1.z; f[7] = (_Float16)v1.w;
    return f;
}

template <int NS>
__device__ __forceinline__ void compute_sub(const f16x8* __restrict__ A,
                                            const f16x8* __restrict__ B,
                                            f4v* __restrict__ acc) {
#pragma unroll
    for (int i = 0; i < NS; ++i)
#pragma unroll
        for (int c = 0; c < 5; ++c)
            acc[i * 5 + c] = __builtin_amdgcn_mfma_f32_16x16x32_f16(
                A[i], B[c], acc[i * 5 + c], 0, 0, 0);
}

// One wave: strips [SG0, SG0+NS) x 5 ct tiles of one (bi,bt).
// ALL operands direct global->VGPR: the fragment gather (row*DD + lq*8) IS
// the MFMA operand layout, so LDS staging only ever paid for multicast —
// which measured as a net loss (R6..R10 plateau, every pipe <25% busy).
// Register double-buffer at CHUNK depth: 9 frag loads of sub k+1 in flight
// across the whole compute of sub k (~400 SIMD-cyc; covers L2 latency; the
// compiler auto-emits fine-grained vmcnt since deps are register-tracked).
// NO LDS, NO barriers in the K loop — waves fully self-paced.
// Reductions are mask-free: clamped pad rows/cols duplicate real ones
// (idempotent under max — validated R8); means exclude pads by index.
template <bool PRE, int SG0, int NS>
__device__ __forceinline__ void run_wave(
    const float* __restrict__ imgF, const float* __restrict__ txtF,
    const _Float16* __restrict__ h16,
    int bi, int bt, int wave, int lane,
    float* __restrict__ rp, float* __restrict__ cp)
{
    const int lm = lane & 15;
    const int lq = lane >> 4;

    int offA[NS], offB[5];
#pragma unroll
    for (int i = 0; i < NS; ++i) {
        int q = (SG0 + i) * 16 + lm; q = q > (N1 - 1) ? (N1 - 1) : q;
        offA[i] = (bi * N1 + q) * DD + lq * 8;
    }
#pragma unroll
    for (int c = 0; c < 5; ++c) {
        int r = c * 16 + lm; r = r > (N2 - 1) ? (N2 - 1) : r;
        offB[c] = (bt * N2 + r) * DD + lq * 8;
    }

    f4v acc[NS * 5];
#pragma unroll
    for (int i = 0; i < NS * 5; ++i) acc[i] = (f4v){0.f, 0.f, 0.f, 0.f};

    f16x8 A0[NS], B0[5], A1[NS], B1[5];

    auto load = [&](int kc, f16x8* A, f16x8* B) {
        const int k0 = kc * 32;
        if constexpr (PRE) {
#pragma unroll
            for (int i = 0; i < NS; ++i)
                A[i] = *(const f16x8*)(h16 + offA[i] + k0);
#pragma unroll
            for (int c = 0; c < 5; ++c)
                B[c] = *(const f16x8*)(h16 + IMGN + offB[c] + k0);
        } else {
#pragma unroll
            for (int i = 0; i < NS; ++i) A[i] = cvt8(imgF + offA[i] + k0);
#pragma unroll
            for (int c = 0; c < 5; ++c) B[c] = cvt8(txtF + offB[c] + k0);
        }
    };

    // ---- K loop: 16 subs of K=32, register ping-pong, chunk-deep prefetch ----
    load(0, A0, B0);
#pragma unroll 1
    for (int kc = 0; kc < 16; kc += 2) {
        load(kc + 1, A1, B1);            // in flight across compute of kc
        compute_sub<NS>(A0, B0, acc);
        if (kc + 2 < 16) load(kc + 2, A0, B0);
        compute_sub<NS>(A1, B1, acc);
    }

    // ---- per-wave reduction partials ----
    // C/D layout: col = lane&15, row_in_tile = (lane>>4)*4 + reg.
#pragma unroll
    for (int i = 0; i < NS; ++i) {
        float rowm[4] = {-INFINITY, -INFINITY, -INFINITY, -INFINITY};
#pragma unroll
        for (int c = 0; c < 5; ++c) {
            f4v a = acc[i * 5 + c];
#pragma unroll
            for (int r = 0; r < 4; ++r) rowm[r] = fmaxf(rowm[r], a[r]);
        }
#pragma unroll
        for (int r = 0; r < 4; ++r) {
            float m = rowm[r];
            m = fmaxf(m, __shfl_xor(m, 1));
            m = fmaxf(m, __shfl_xor(m, 2));
            m = fmaxf(m, __shfl_xor(m, 4));
            m = fmaxf(m, __shfl_xor(m, 8));
            if (lm == 0) rp[(SG0 + i) * 16 + lq * 4 + r] = m;
        }
    }
    float colm[5];
#pragma unroll
    for (int c = 0; c < 5; ++c) colm[c] = -INFINITY;
#pragma unroll
    for (int i = 0; i < NS; ++i)
#pragma unroll
        for (int c = 0; c < 5; ++c) {
            f4v a = acc[i * 5 + c];
#pragma unroll
            for (int r = 0; r < 4; ++r) colm[c] = fmaxf(colm[c], a[r]);
        }
#pragma unroll
    for (int c = 0; c < 5; ++c) {
        float m = colm[c];
        m = fmaxf(m, __shfl_xor(m, 16));
        m = fmaxf(m, __shfl_xor(m, 32));
        if (lq == 0) cp[wave * 80 + c * 16 + lm] = m;
    }
}

// One block per (bi, bt): 4 waves own strip groups {0-3, 4-6, 7-9, 10-12}.
// __launch_bounds__(256,2): VGPR cap 256 — acc[20]+frag dbuf (~180 regs)
// must stay in registers; WRITE_SIZE ballooning = spill (R5/R8 tripwire).
template <bool PRE>
__global__ __launch_bounds__(256, 2) void sim_mfma_kernel(
    const float* __restrict__ imgF, const float* __restrict__ txtF,
    const _Float16* __restrict__ h16,   // [img | txt] concatenated
    float* __restrict__ i2t, float* __restrict__ t2i)
{
    // ---- XCD-locality swizzle (R9: halves unique L3->L2 traffic) ----
    const int id  = blockIdx.x;
    const int xcd = id & 7;
    const int lid = id >> 3;           // 0..1151
    const int btq = lid / 48;          // 0..23
    const int w   = lid % 48;          // 4 bt x 12 bi
    const int bt  = btq * 4 + (w & 3);
    const int bi  = xcd * 12 + (w >> 2);

    const int tid = threadIdx.x;
    const int wave = tid >> 6, lane = tid & 63;

    __shared__ float rp[208];     // rowmax per padded row (strips wave-exclusive)
    __shared__ float cp[4 * 80];  // colmax partial per wave
    __shared__ float scol[80];
    __shared__ float sws[4];

    if (wave == 0)      run_wave<PRE, 0, 4>(imgF, txtF, h16, bi, bt, wave, lane, rp, cp);
    else if (wave == 1) run_wave<PRE, 4, 3>(imgF, txtF, h16, bi, bt, wave, lane, rp, cp);
    else if (wave == 2) run_wave<PRE, 7, 3>(imgF, txtF, h16, bi, bt, wave, lane, rp, cp);
    else                run_wave<PRE, 10, 3>(imgF, txtF, h16, bi, bt, wave, lane, rp, cp);
    __syncthreads();   // the ONLY cross-wave sync

    // i2t: mean over q<196 of rowmax
    float v = (tid < N1) ? rp[tid] : 0.f;
    v += __shfl_xor(v, 1);  v += __shfl_xor(v, 2);  v += __shfl_xor(v, 4);
    v += __shfl_xor(v, 8);  v += __shfl_xor(v, 16); v += __shfl_xor(v, 32);
    if (lane == 0) sws[wave] = v;
    if (tid < 80) {
        scol[tid] = fmaxf(fmaxf(cp[tid], cp[80 + tid]),
                          fmaxf(cp[160 + tid], cp[240 + tid]));
    }
    __syncthreads();
    if (tid == 0)
        i2t[bi * BB + bt] = (sws[0] + sws[1] + sws[2] + sws[3]) * (1.f / (float)N1);
    if (wave == 0) {
        float cv = scol[lane] + ((lane < N2 - 64) ? scol[64 + lane] : 0.f);
        cv += __shfl_xor(cv, 1);  cv += __shfl_xor(cv, 2);  cv += __shfl_xor(cv, 4);
        cv += __shfl_xor(cv, 8);  cv += __shfl_xor(cv, 16); cv += __shfl_xor(cv, 32);
        if (lane == 0) t2i[bt * BB + bi] = cv * (1.f / (float)N2);
    }
}

// CE with arange labels over both [B,B] logit matrices.
__global__ __launch_bounds__(256) void ce_kernel(
    const float* __restrict__ i2t, const float* __restrict__ t2i,
    float* __restrict__ out)
{
    const int tid = threadIdx.x;
    const int wid = tid >> 6;
    const int lane = tid & 63;

    float contrib = 0.f;
    if (tid < 2 * BB) {
        const float* M = (tid < BB) ? i2t : t2i;
        const int b = (tid < BB) ? tid : tid - BB;
        const float* row = M + b * BB;
        float mx = row[0];
#pragma unroll 1
        for (int c = 1; c < BB; ++c) mx = fmaxf(mx, row[c]);
        float s = 0.f;
#pragma unroll 1
        for (int c = 0; c < BB; ++c) s += expf(row[c] - mx);
        float lse = mx + logf(s);
        contrib = row[b] - lse;
    }
    contrib += __shfl_xor(contrib, 1);
    contrib += __shfl_xor(contrib, 2);
    contrib += __shfl_xor(contrib, 4);
    contrib += __shfl_xor(contrib, 8);
    contrib += __shfl_xor(contrib, 16);
    contrib += __shfl_xor(contrib, 32);

    __shared__ float s_part[4];
    if (lane == 0) s_part[wid] = contrib;
    __syncthreads();
    if (tid == 0) {
        float total = s_part[0] + s_part[1] + s_part[2] + s_part[3];
        out[0] = -total * (1.f / (float)(2 * BB));
    }
}

extern "C" void kernel_launch(void* const* d_in, const int* in_sizes, int n_in,
                              void* d_out, int out_size, void* d_ws, size_t ws_size,
                              hipStream_t stream) {
    const float* img = (const float*)d_in[0];   // [96,196,512] fp32
    const float* txt = (const float*)d_in[1];   // [96,77,512] fp32
    float* i2t = (float*)d_ws;                  // [96,96]
    float* t2i = i2t + BB * BB;                 // [96,96]

    const size_t conv_off = 2 * BB * BB * sizeof(float);   // 16B-aligned
    const size_t need = conv_off + (size_t)(IMGN + TXTN) * sizeof(_Float16);

    if (ws_size >= need) {
        _Float16* h16 = (_Float16*)((char*)d_ws + conv_off);
        convert_kernel<<<(IMGN / 4 + 255) / 256, 256, 0, stream>>>(img, h16, IMGN);
        convert_kernel<<<(TXTN / 4 + 255) / 256, 256, 0, stream>>>(txt, h16 + IMGN, TXTN);
        sim_mfma_kernel<true><<<BB * BB, 256, 0, stream>>>(img, txt, h16, i2t, t2i);
    } else {
        sim_mfma_kernel<false><<<BB * BB, 256, 0, stream>>>(img, txt, nullptr, i2t, t2i);
    }
    ce_kernel<<<1, 256, 0, stream>>>(i2t, t2i, (float*)d_out);
}